// Round 5
// baseline (145.045 us; speedup 1.0000x reference)
//
#include <hip/hip_runtime.h>
#include <hip/hip_bf16.h>

// Problem constants (fixed: H=W=128, C=64, K=3, HID=256, OUT_C=3, scale=2)
#define H_IN 128
#define W_IN 128
#define C_IN 64
#define HID 256
#define OUT_C 3
#define OUT_W 256
#define NW 1728   // 3*3*64*3 weights per parity
#define PPW 8     // input pixels per wave in the einsum phase
#define NBLK 512
#define NPROD 27

// ws layout (floats): [0, 4*NW) = wts.  At byte offset 32768: sync region =
//   int counter (1 line), then NBLK flag lines of 32 ints (128 B) each.
#define SYNC_FOFF 8192                       // float offset of sync region
#define SYNC_BYTES ((32 + NBLK * 32) * 4)    // 65664 bytes, memset each call

__device__ __forceinline__ float rdlane(float v, int l) {
    return __int_as_float(__builtin_amdgcn_readlane(__float_as_int(v), l));
}

// ---------------------------------------------------------------------------
// Phase A: blocks 0..26 compute the 4-parity MLP weights -> wts.
// ---------------------------------------------------------------------------
__device__ __forceinline__ void mlp_phase(
    const float* __restrict__ k1, const float* __restrict__ b1,
    const float* __restrict__ k2, const float* __restrict__ b2,
    const float* __restrict__ k3, const float* __restrict__ b3,
    float* __restrict__ wts, int bid, int tid)
{
    __shared__ float sPart[4][4][256];   // [wave][par][n]
    __shared__ float sH2[4][256];        // [par][n]
    const int lane = tid & 63;
    const int w    = tid >> 6;

    // h1 for this wave's m-slice (m = w*64+lane), 4 parities
    const int m = w * 64 + lane;
    const float k10 = k1[m], k11 = k1[HID + m], k12 = k1[2 * HID + m];
    const float b1m = b1[m];
    float h1r[4];
    h1r[0] = fmaxf(0.5f * k12 + b1m, 0.0f);
    h1r[1] = fmaxf(0.5f * k11 + 0.5f * k12 + b1m, 0.0f);
    h1r[2] = fmaxf(0.5f * k10 + 0.5f * k12 + b1m, 0.0f);
    h1r[3] = fmaxf(0.5f * k10 + 0.5f * k11 + 0.5f * k12 + b1m, 0.0f);

    // partial h2: wave w covers m in [64w,64w+64), cols 4*lane..+3, 4 parities
    float4 acc[4];
#pragma unroll
    for (int p = 0; p < 4; ++p) acc[p] = make_float4(0.f, 0.f, 0.f, 0.f);
    const float* k2p = k2 + (w * 64) * HID + 4 * lane;
#pragma unroll
    for (int i = 0; i < 64; ++i) {
        const float4 kv = *reinterpret_cast<const float4*>(k2p + i * HID);
#pragma unroll
        for (int p = 0; p < 4; ++p) {
            const float hm = rdlane(h1r[p], i);
            acc[p].x = fmaf(hm, kv.x, acc[p].x);
            acc[p].y = fmaf(hm, kv.y, acc[p].y);
            acc[p].z = fmaf(hm, kv.z, acc[p].z);
            acc[p].w = fmaf(hm, kv.w, acc[p].w);
        }
    }
#pragma unroll
    for (int p = 0; p < 4; ++p)
        *reinterpret_cast<float4*>(&sPart[w][p][4 * lane]) = acc[p];
    __syncthreads();

    // reduce 4 waves -> h2 (relu)
    const float b2v = b2[tid];
#pragma unroll
    for (int p = 0; p < 4; ++p) {
        const float s = b2v + sPart[0][p][tid] + sPart[1][p][tid]
                      + sPart[2][p][tid] + sPart[3][p][tid];
        sH2[p][tid] = fmaxf(s, 0.0f);
    }
    __syncthreads();

    // this block's 64 k3 columns; wave w covers its m-range
    const int colbase = bid * 64;
    float h2r[4];
#pragma unroll
    for (int p = 0; p < 4; ++p) h2r[p] = sH2[p][w * 64 + lane];

    float a0 = 0.f, a1 = 0.f, a2 = 0.f, a3 = 0.f;
    const float* kp = k3 + (size_t)(w * 64) * NW + colbase + lane;
#pragma unroll
    for (int i = 0; i < 64; ++i) {
        const float kv = kp[(size_t)i * NW];
        a0 = fmaf(rdlane(h2r[0], i), kv, a0);
        a1 = fmaf(rdlane(h2r[1], i), kv, a1);
        a2 = fmaf(rdlane(h2r[2], i), kv, a2);
        a3 = fmaf(rdlane(h2r[3], i), kv, a3);
    }
    sPart[w][0][lane] = a0; sPart[w][1][lane] = a1;
    sPart[w][2][lane] = a2; sPart[w][3][lane] = a3;
    __syncthreads();

    const int p = tid >> 6, c = tid & 63;
    const int n = colbase + c;
    const float s = b3[n] + sPart[0][p][c] + sPart[1][p][c]
                  + sPart[2][p][c] + sPart[3][p][c];
    // n = ((pp*3+q)*64 + ch)*3 + o  ->  [par][o][pq][ch]
    const int o = n % 3;
    const int rest = n / 3;
    const int cch = rest & 63;
    const int pq = rest >> 6;
    wts[p * NW + (o * 9 + pq) * 64 + cch] = s;
}

// ---------------------------------------------------------------------------
// Phase C: the einsum. Wave = 4 parities x 16 c4-chunks, PPW pixels/wave.
// Column ring buffer (3 loads/pixel). If WAIT: first two columns prefetched
// BEFORE the private-flag spin (overlaps phase A).
// ---------------------------------------------------------------------------
template <bool WAIT>
__device__ __forceinline__ void einsum_phase(
    const float* __restrict__ feat, const float* __restrict__ wts,
    float* __restrict__ out, int* myflag, int bid, int tid)
{
    const int lane = tid & 63;
    const int w    = tid >> 6;
    const int gw   = bid * 4 + w;            // 0..2047
    const int iy   = gw >> 4;                // input row 0..127
    const int ix0  = (gw & 15) * PPW;        // input col base
    const int par  = lane >> 4;              // 0..3
    const int c4   = lane & 15;              // channel quad
    const int pi = par >> 1, pj = par & 1;

    const bool rv0 = iy > 0, rv2 = iy < H_IN - 1;
    const float4 fz = make_float4(0.f, 0.f, 0.f, 0.f);
    const float* frow0 = feat + ((iy - 1) * W_IN) * C_IN + c4 * 4;
    const float* frow1 = feat + ((iy    ) * W_IN) * C_IN + c4 * 4;
    const float* frow2 = feat + ((iy + 1) * W_IN) * C_IN + c4 * 4;

    float4 fc0[3], fc1[3], fc2[3];
    auto ldcol = [&](int cc, float4& a, float4& b, float4& c) {
        if ((unsigned)cc < (unsigned)W_IN) {
            a = rv0 ? *reinterpret_cast<const float4*>(frow0 + cc * C_IN) : fz;
            b =       *reinterpret_cast<const float4*>(frow1 + cc * C_IN);
            c = rv2 ? *reinterpret_cast<const float4*>(frow2 + cc * C_IN) : fz;
        } else { a = fz; b = fz; c = fz; }
    };
    // Prefetch first two columns (overlaps the producer wait below).
    ldcol(ix0 - 1, fc0[0], fc1[0], fc2[0]);
    ldcol(ix0,     fc0[1], fc1[1], fc2[1]);

    if (WAIT) {
        // Poll OWN 128-B flag line, rarely (s_sleep(16) ~ 1024 cy between
        // polls): no same-line contention, no fabric flooding.
        if (tid == 0) {
            int it = 0;
            while (__hip_atomic_load(myflag, __ATOMIC_ACQUIRE,
                                     __HIP_MEMORY_SCOPE_AGENT) == 0
                   && it < 32768) {
                __builtin_amdgcn_s_sleep(16);
                ++it;
            }
        }
        __syncthreads();
        __threadfence();   // acquire side: refresh caches before wts reads
    }

    float4 wreg[3][9];
#pragma unroll
    for (int o = 0; o < 3; ++o)
#pragma unroll
        for (int pq = 0; pq < 9; ++pq)
            wreg[o][pq] = *reinterpret_cast<const float4*>(
                wts + ((par * 3 + o) * 9 + pq) * 64 + c4 * 4);

#pragma unroll
    for (int g = 0; g < PPW; ++g) {
        const int sNew = (g + 2) % 3;
        ldcol(ix0 + g + 1, fc0[sNew], fc1[sNew], fc2[sNew]);

        float acc0 = 0.f, acc1 = 0.f, acc2 = 0.f;
#pragma unroll
        for (int q = 0; q < 3; ++q) {
            const int s = (g + q) % 3;
            const float4 f0 = fc0[s], f1 = fc1[s], f2 = fc2[s];
            const int pq0 = q, pq1 = 3 + q, pq2 = 6 + q;
            acc0 = fmaf(f0.x, wreg[0][pq0].x, acc0);
            acc0 = fmaf(f0.y, wreg[0][pq0].y, acc0);
            acc0 = fmaf(f0.z, wreg[0][pq0].z, acc0);
            acc0 = fmaf(f0.w, wreg[0][pq0].w, acc0);
            acc1 = fmaf(f0.x, wreg[1][pq0].x, acc1);
            acc1 = fmaf(f0.y, wreg[1][pq0].y, acc1);
            acc1 = fmaf(f0.z, wreg[1][pq0].z, acc1);
            acc1 = fmaf(f0.w, wreg[1][pq0].w, acc1);
            acc2 = fmaf(f0.x, wreg[2][pq0].x, acc2);
            acc2 = fmaf(f0.y, wreg[2][pq0].y, acc2);
            acc2 = fmaf(f0.z, wreg[2][pq0].z, acc2);
            acc2 = fmaf(f0.w, wreg[2][pq0].w, acc2);

            acc0 = fmaf(f1.x, wreg[0][pq1].x, acc0);
            acc0 = fmaf(f1.y, wreg[0][pq1].y, acc0);
            acc0 = fmaf(f1.z, wreg[0][pq1].z, acc0);
            acc0 = fmaf(f1.w, wreg[0][pq1].w, acc0);
            acc1 = fmaf(f1.x, wreg[1][pq1].x, acc1);
            acc1 = fmaf(f1.y, wreg[1][pq1].y, acc1);
            acc1 = fmaf(f1.z, wreg[1][pq1].z, acc1);
            acc1 = fmaf(f1.w, wreg[1][pq1].w, acc1);
            acc2 = fmaf(f1.x, wreg[2][pq1].x, acc2);
            acc2 = fmaf(f1.y, wreg[2][pq1].y, acc2);
            acc2 = fmaf(f1.z, wreg[2][pq1].z, acc2);
            acc2 = fmaf(f1.w, wreg[2][pq1].w, acc2);

            acc0 = fmaf(f2.x, wreg[0][pq2].x, acc0);
            acc0 = fmaf(f2.y, wreg[0][pq2].y, acc0);
            acc0 = fmaf(f2.z, wreg[0][pq2].z, acc0);
            acc0 = fmaf(f2.w, wreg[0][pq2].w, acc0);
            acc1 = fmaf(f2.x, wreg[1][pq2].x, acc1);
            acc1 = fmaf(f2.y, wreg[1][pq2].y, acc1);
            acc1 = fmaf(f2.z, wreg[1][pq2].z, acc1);
            acc1 = fmaf(f2.w, wreg[1][pq2].w, acc1);
            acc2 = fmaf(f2.x, wreg[2][pq2].x, acc2);
            acc2 = fmaf(f2.y, wreg[2][pq2].y, acc2);
            acc2 = fmaf(f2.z, wreg[2][pq2].z, acc2);
            acc2 = fmaf(f2.w, wreg[2][pq2].w, acc2);
        }

        // 8-shuffle reduction over 16 lanes for 3 values
        acc0 += __shfl_xor(acc0, 1); acc0 += __shfl_xor(acc0, 2);
        acc1 += __shfl_xor(acc1, 1); acc1 += __shfl_xor(acc1, 2);
        acc2 += __shfl_xor(acc2, 1); acc2 += __shfl_xor(acc2, 2);
        const int j = c4 & 3;
        float v = (j == 0) ? acc0 : ((j == 1) ? acc1 : acc2);
        v += __shfl_xor(v, 4);
        v += __shfl_xor(v, 8);
        if (c4 < 3) {
            const int oy = 2 * iy + pi;
            const int ox = 2 * (ix0 + g) + pj;
            out[(oy * OUT_W + ox) * OUT_C + c4] = v;
        }
    }
}

// ===========================================================================
// Fused cooperative kernel with private-flag fanout barrier.
// ===========================================================================
__global__ __launch_bounds__(256, 2) void fused_kernel(
    const float* __restrict__ feat,
    const float* __restrict__ k1, const float* __restrict__ b1,
    const float* __restrict__ k2, const float* __restrict__ b2,
    const float* __restrict__ k3, const float* __restrict__ b3,
    float* __restrict__ wts, int* syncb, float* __restrict__ out)
{
    __shared__ int sLast;
    const int tid = threadIdx.x;
    const int bid = blockIdx.x;
    int* counter = syncb;                 // one 128-B line
    int* flags   = syncb + 32;            // NBLK lines of 32 ints

    if (bid < NPROD) {
        mlp_phase(k1, b1, k2, b2, k3, b3, wts, bid, tid);
        __threadfence();                  // release this thread's wts stores
        if (tid == 0) sLast = 0;
        __syncthreads();
        if (tid == 0) {
            const int old = __hip_atomic_fetch_add(
                counter, 1, __ATOMIC_ACQ_REL, __HIP_MEMORY_SCOPE_AGENT);
            if (old == NPROD - 1) sLast = 1;
        }
        __syncthreads();
        if (sLast) {
            // Last producer fans out: one release store per consumer's line.
            for (int b = tid; b < NBLK; b += 256)
                __hip_atomic_store(&flags[b * 32], 1, __ATOMIC_RELEASE,
                                   __HIP_MEMORY_SCOPE_AGENT);
        }
    }

    einsum_phase<true>(feat, wts, out, &flags[bid * 32], bid, tid);
}

// ===========================================================================
// Non-cooperative fallback: 2 kernels.
// ===========================================================================
__global__ __launch_bounds__(256) void mlp_fb(
    const float* __restrict__ k1, const float* __restrict__ b1,
    const float* __restrict__ k2, const float* __restrict__ b2,
    const float* __restrict__ k3, const float* __restrict__ b3,
    float* __restrict__ wts)
{
    mlp_phase(k1, b1, k2, b2, k3, b3, wts, blockIdx.x, threadIdx.x);
}

__global__ __launch_bounds__(256) void upscale_fb(
    const float* __restrict__ feat, const float* __restrict__ wts,
    float* __restrict__ out)
{
    einsum_phase<false>(feat, wts, out, nullptr, blockIdx.x, threadIdx.x);
}

// ---------------------------------------------------------------------------
extern "C" void kernel_launch(void* const* d_in, const int* in_sizes, int n_in,
                              void* d_out, int out_size, void* d_ws, size_t ws_size,
                              hipStream_t stream)
{
    const float* feat = (const float*)d_in[0];
    const float* k1   = (const float*)d_in[1];
    const float* b1   = (const float*)d_in[2];
    const float* k2   = (const float*)d_in[3];
    const float* b2   = (const float*)d_in[4];
    const float* k3   = (const float*)d_in[5];
    const float* b3   = (const float*)d_in[6];
    float* out  = (float*)d_out;
    float* ws   = (float*)d_ws;
    float* wts  = ws;                          // 4*NW floats
    int*   syncb = (int*)(ws + SYNC_FOFF);     // counter + per-block flags

    hipMemsetAsync(syncb, 0, SYNC_BYTES, stream);

    void* args[] = {(void*)&feat, (void*)&k1, (void*)&b1, (void*)&k2,
                    (void*)&b2, (void*)&k3, (void*)&b3, (void*)&wts,
                    (void*)&syncb, (void*)&out};
    hipError_t err = hipLaunchCooperativeKernel(
        (const void*)fused_kernel, dim3(NBLK), dim3(256), args, 0, stream);
    if (err != hipSuccess) {
        mlp_fb<<<NPROD, 256, 0, stream>>>(k1, b1, k2, b2, k3, b3, wts);
        upscale_fb<<<NBLK, 256, 0, stream>>>(feat, wts, out);
    }
}

// Round 7
// 26.792 us; speedup vs baseline: 5.4138x; 5.4138x over previous
//
#include <hip/hip_runtime.h>
#include <hip/hip_bf16.h>

// Problem constants (fixed: H=W=128, C=64, K=3, HID=256, OUT_C=3, scale=2)
#define H_IN 128
#define W_IN 128
#define C_IN 64
#define HID 256
#define OUT_C 3
#define OUT_W 256
#define NW 1728   // 3*3*64*3 weights per parity
#define PPW 8     // input pixels per wave in the einsum phase

__device__ __forceinline__ float rdlane(float v, int l) {
    return __int_as_float(__builtin_amdgcn_readlane(__float_as_int(v), l));
}

// ---------------------------------------------------------------------------
// A: partial h2 sums (no bias/relu). Grid 16 blocks (par=b>>2, mc=b&3) x 256.
// part[(par*4+mc)*256 + col] = sum_{m in chunk mc} h1[par][m] * k2[m][col]
// (validated in round 2)
// ---------------------------------------------------------------------------
__global__ __launch_bounds__(256) void mlp12_kernel(
    const float* __restrict__ k1, const float* __restrict__ b1,
    const float* __restrict__ k2, float* __restrict__ part)
{
    __shared__ float sP[4][64][4];
    const int tid  = threadIdx.x;
    const int lane = tid & 63, w = tid >> 6;
    const int par  = blockIdx.x >> 2, mc = blockIdx.x & 3;
    const float vi = 0.5f * (float)(par >> 1);
    const float vj = 0.5f * (float)(par & 1);

    // h1[par][mc*64 + lane], replicated across the 4 waves
    const int m0 = mc * 64 + lane;
    const float hreg = fmaxf(vi * k1[m0] + vj * k1[HID + m0]
                             + 0.5f * k1[2 * HID + m0] + b1[m0], 0.0f);

    // wave w accumulates its 16-m slice for cols [4*lane, 4*lane+4)
    float4 acc = make_float4(0.f, 0.f, 0.f, 0.f);
    const int mbase = mc * 64 + w * 16;
#pragma unroll
    for (int i = 0; i < 16; ++i) {
        const float hm = rdlane(hreg, w * 16 + i);
        const float4 kv = *reinterpret_cast<const float4*>(
            k2 + (mbase + i) * HID + lane * 4);
        acc.x = fmaf(hm, kv.x, acc.x);
        acc.y = fmaf(hm, kv.y, acc.y);
        acc.z = fmaf(hm, kv.z, acc.z);
        acc.w = fmaf(hm, kv.w, acc.w);
    }
    *reinterpret_cast<float4*>(&sP[w][lane][0]) = acc;
    __syncthreads();

    const float s = sP[0][tid >> 2][tid & 3] + sP[1][tid >> 2][tid & 3]
                  + sP[2][tid >> 2][tid & 3] + sP[3][tid >> 2][tid & 3];
    part[(par * 4 + mc) * HID + tid] = s;
}

// ---------------------------------------------------------------------------
// A2: h2[p][n] = relu(b2[n] + sum_mc part[p][mc][n]).  Grid 4 blocks x 256.
// ---------------------------------------------------------------------------
__global__ __launch_bounds__(256) void h2reduce_kernel(
    const float* __restrict__ part, const float* __restrict__ b2,
    float* __restrict__ h2)
{
    const int p = blockIdx.x, n = threadIdx.x;
    const float s = b2[n]
                  + part[(p * 4 + 0) * HID + n] + part[(p * 4 + 1) * HID + n]
                  + part[(p * 4 + 2) * HID + n] + part[(p * 4 + 3) * HID + n];
    h2[p * HID + n] = fmaxf(s, 0.0f);
}

// ---------------------------------------------------------------------------
// B: wide layer-3. Grid 432 blocks x 256 threads; block b covers k3 columns
// [4b, 4b+4). Thread t: c = t&3, m0 = 4*(t>>2) (wave w naturally covers
// m in [64w, 64w+64) -- FIXED: previous round added w*64 twice).
// partial[p] = sum_j h2[p][m0+j] * k3[m0+j][col]; reduce 16 same-c lanes via
// shfl_xor(4,8,16,32) within wave + LDS across the 4 waves.
// ---------------------------------------------------------------------------
__global__ __launch_bounds__(256) void mlp3_wide_kernel(
    const float* __restrict__ k3, const float* __restrict__ b3,
    const float* __restrict__ h2, float* __restrict__ wout)
{
    __shared__ float sR[4][4][4];   // [wave][p][c]
    const int tid  = threadIdx.x;
    const int lane = tid & 63, w = tid >> 6;
    const int c    = tid & 3;
    const int m0   = tid & 0xFC;                    // 4*(tid>>2): [0,256) once
    const int n    = blockIdx.x * 4 + c;            // k3 column 0..1727

    // h2 fragments: 4 parities x float4
    float4 h4[4];
#pragma unroll
    for (int p = 0; p < 4; ++p)
        h4[p] = *reinterpret_cast<const float4*>(h2 + p * HID + m0);

    // k3 values for this thread's 4 m's
    float kv[4];
#pragma unroll
    for (int j = 0; j < 4; ++j)
        kv[j] = k3[(size_t)(m0 + j) * NW + n];

    float pr[4];
#pragma unroll
    for (int p = 0; p < 4; ++p) {
        pr[p] = h4[p].x * kv[0] + h4[p].y * kv[1]
              + h4[p].z * kv[2] + h4[p].w * kv[3];
    }

    // reduce the 16 same-c lanes within the wave
#pragma unroll
    for (int p = 0; p < 4; ++p) {
        pr[p] += __shfl_xor(pr[p], 4);
        pr[p] += __shfl_xor(pr[p], 8);
        pr[p] += __shfl_xor(pr[p], 16);
        pr[p] += __shfl_xor(pr[p], 32);
    }
    if (lane < 4) {
#pragma unroll
        for (int p = 0; p < 4; ++p) sR[w][p][lane] = pr[p];
    }
    __syncthreads();

    // final: threads 0..15 -> (p = t>>2, c = t&3)
    if (tid < 16) {
        const int fp = tid >> 2, fc = tid & 3;
        const int fn = blockIdx.x * 4 + fc;
        const float total = b3[fn] + sR[0][fp][fc] + sR[1][fp][fc]
                          + sR[2][fp][fc] + sR[3][fp][fc];
        // fn = ((pp*3+q)*64 + ch)*3 + o  ->  [par][o][pq][ch]
        const int o = fn % 3;
        const int rest = fn / 3;
        const int cch = rest & 63;
        const int pq = rest >> 6;
        wout[fp * NW + (o * 9 + pq) * 64 + cch] = total;
    }
}

// ---------------------------------------------------------------------------
// C: the einsum. Wave = 4 parities x 16 c4-chunks, PPW pixels/wave, column
// ring buffer (3 loads/pixel), weights register-stationary. (validated)
// Grid 512 x 256.
// ---------------------------------------------------------------------------
__global__ __launch_bounds__(256) void upscale_kernel(
    const float* __restrict__ feat, const float* __restrict__ wts,
    float* __restrict__ out)
{
    const int tid  = threadIdx.x;
    const int lane = tid & 63;
    const int w    = tid >> 6;
    const int gw   = blockIdx.x * 4 + w;     // 0..2047
    const int iy   = gw >> 4;                // input row 0..127
    const int ix0  = (gw & 15) * PPW;        // input col base
    const int par  = lane >> 4;              // 0..3
    const int c4   = lane & 15;              // channel quad
    const int pi = par >> 1, pj = par & 1;

    const bool rv0 = iy > 0, rv2 = iy < H_IN - 1;
    const float4 fz = make_float4(0.f, 0.f, 0.f, 0.f);
    const float* frow0 = feat + ((iy - 1) * W_IN) * C_IN + c4 * 4;
    const float* frow1 = feat + ((iy    ) * W_IN) * C_IN + c4 * 4;
    const float* frow2 = feat + ((iy + 1) * W_IN) * C_IN + c4 * 4;

    float4 fc0[3], fc1[3], fc2[3];
    auto ldcol = [&](int cc, float4& a, float4& b, float4& c) {
        if ((unsigned)cc < (unsigned)W_IN) {
            a = rv0 ? *reinterpret_cast<const float4*>(frow0 + cc * C_IN) : fz;
            b =       *reinterpret_cast<const float4*>(frow1 + cc * C_IN);
            c = rv2 ? *reinterpret_cast<const float4*>(frow2 + cc * C_IN) : fz;
        } else { a = fz; b = fz; c = fz; }
    };
    ldcol(ix0 - 1, fc0[0], fc1[0], fc2[0]);
    ldcol(ix0,     fc0[1], fc1[1], fc2[1]);

    float4 wreg[3][9];
#pragma unroll
    for (int o = 0; o < 3; ++o)
#pragma unroll
        for (int pq = 0; pq < 9; ++pq)
            wreg[o][pq] = *reinterpret_cast<const float4*>(
                wts + ((par * 3 + o) * 9 + pq) * 64 + c4 * 4);

#pragma unroll
    for (int g = 0; g < PPW; ++g) {
        const int sNew = (g + 2) % 3;
        ldcol(ix0 + g + 1, fc0[sNew], fc1[sNew], fc2[sNew]);

        float acc0 = 0.f, acc1 = 0.f, acc2 = 0.f;
#pragma unroll
        for (int q = 0; q < 3; ++q) {
            const int s = (g + q) % 3;
            const float4 f0 = fc0[s], f1 = fc1[s], f2 = fc2[s];
            const int pq0 = q, pq1 = 3 + q, pq2 = 6 + q;
            acc0 = fmaf(f0.x, wreg[0][pq0].x, acc0);
            acc0 = fmaf(f0.y, wreg[0][pq0].y, acc0);
            acc0 = fmaf(f0.z, wreg[0][pq0].z, acc0);
            acc0 = fmaf(f0.w, wreg[0][pq0].w, acc0);
            acc1 = fmaf(f0.x, wreg[1][pq0].x, acc1);
            acc1 = fmaf(f0.y, wreg[1][pq0].y, acc1);
            acc1 = fmaf(f0.z, wreg[1][pq0].z, acc1);
            acc1 = fmaf(f0.w, wreg[1][pq0].w, acc1);
            acc2 = fmaf(f0.x, wreg[2][pq0].x, acc2);
            acc2 = fmaf(f0.y, wreg[2][pq0].y, acc2);
            acc2 = fmaf(f0.z, wreg[2][pq0].z, acc2);
            acc2 = fmaf(f0.w, wreg[2][pq0].w, acc2);

            acc0 = fmaf(f1.x, wreg[0][pq1].x, acc0);
            acc0 = fmaf(f1.y, wreg[0][pq1].y, acc0);
            acc0 = fmaf(f1.z, wreg[0][pq1].z, acc0);
            acc0 = fmaf(f1.w, wreg[0][pq1].w, acc0);
            acc1 = fmaf(f1.x, wreg[1][pq1].x, acc1);
            acc1 = fmaf(f1.y, wreg[1][pq1].y, acc1);
            acc1 = fmaf(f1.z, wreg[1][pq1].z, acc1);
            acc1 = fmaf(f1.w, wreg[1][pq1].w, acc1);
            acc2 = fmaf(f1.x, wreg[2][pq1].x, acc2);
            acc2 = fmaf(f1.y, wreg[2][pq1].y, acc2);
            acc2 = fmaf(f1.z, wreg[2][pq1].z, acc2);
            acc2 = fmaf(f1.w, wreg[2][pq1].w, acc2);

            acc0 = fmaf(f2.x, wreg[0][pq2].x, acc0);
            acc0 = fmaf(f2.y, wreg[0][pq2].y, acc0);
            acc0 = fmaf(f2.z, wreg[0][pq2].z, acc0);
            acc0 = fmaf(f2.w, wreg[0][pq2].w, acc0);
            acc1 = fmaf(f2.x, wreg[1][pq2].x, acc1);
            acc1 = fmaf(f2.y, wreg[1][pq2].y, acc1);
            acc1 = fmaf(f2.z, wreg[1][pq2].z, acc1);
            acc1 = fmaf(f2.w, wreg[1][pq2].w, acc1);
            acc2 = fmaf(f2.x, wreg[2][pq2].x, acc2);
            acc2 = fmaf(f2.y, wreg[2][pq2].y, acc2);
            acc2 = fmaf(f2.z, wreg[2][pq2].z, acc2);
            acc2 = fmaf(f2.w, wreg[2][pq2].w, acc2);
        }

        // 8-shuffle reduction over 16 lanes for 3 values
        acc0 += __shfl_xor(acc0, 1); acc0 += __shfl_xor(acc0, 2);
        acc1 += __shfl_xor(acc1, 1); acc1 += __shfl_xor(acc1, 2);
        acc2 += __shfl_xor(acc2, 1); acc2 += __shfl_xor(acc2, 2);
        const int j = c4 & 3;
        float v = (j == 0) ? acc0 : ((j == 1) ? acc1 : acc2);
        v += __shfl_xor(v, 4);
        v += __shfl_xor(v, 8);
        if (c4 < 3) {
            const int oy = 2 * iy + pi;
            const int ox = 2 * (ix0 + g) + pj;
            out[(oy * OUT_W + ox) * OUT_C + c4] = v;
        }
    }
}

// ---------------------------------------------------------------------------
extern "C" void kernel_launch(void* const* d_in, const int* in_sizes, int n_in,
                              void* d_out, int out_size, void* d_ws, size_t ws_size,
                              hipStream_t stream)
{
    const float* feat = (const float*)d_in[0];
    const float* k1   = (const float*)d_in[1];
    const float* b1   = (const float*)d_in[2];
    const float* k2   = (const float*)d_in[3];
    const float* b2   = (const float*)d_in[4];
    const float* k3   = (const float*)d_in[5];
    const float* b3   = (const float*)d_in[6];
    float* out = (float*)d_out;
    float* ws  = (float*)d_ws;
    float* wts  = ws;                       // 4*NW floats, [par][o][pq][c]
    float* part = ws + 4 * NW;              // 16*256 floats
    float* h2   = ws + 4 * NW + 16 * HID;   // 4*256 floats

    mlp12_kernel   <<<16,  256, 0, stream>>>(k1, b1, k2, part);
    h2reduce_kernel<<<4,   256, 0, stream>>>(part, b2, h2);
    mlp3_wide_kernel<<<432, 256, 0, stream>>>(k3, b3, h2, wts);
    upscale_kernel <<<512, 256, 0, stream>>>(feat, wts, out);
}

// Round 8
// 23.377 us; speedup vs baseline: 6.2045x; 1.1461x over previous
//
#include <hip/hip_runtime.h>
#include <hip/hip_bf16.h>

// Problem constants (fixed: H=W=128, C=64, K=3, HID=256, OUT_C=3, scale=2)
#define H_IN 128
#define W_IN 128
#define C_IN 64
#define HID 256
#define OUT_C 3
#define OUT_W 256
#define NW 1728   // 3*3*64*3 weights per parity
#define PPW 8     // input pixels per wave in the einsum phase

__device__ __forceinline__ float rdlane(float v, int l) {
    return __int_as_float(__builtin_amdgcn_readlane(__float_as_int(v), l));
}

// ---------------------------------------------------------------------------
// K1: ENTIRE MLP in one kernel. Grid 108 blocks x 256 threads.
// Each block redundantly computes h2[4][256] (k2 is L1/L2-hot, ~256 KB/block)
// -- phase 1 is the R3/R4/R5-validated code -- then computes its 16 k3
// columns (cols [16b, 16b+16)). Eliminates 2 dependent graph nodes.
// ---------------------------------------------------------------------------
__global__ __launch_bounds__(256) void mlp_all_kernel(
    const float* __restrict__ k1, const float* __restrict__ b1,
    const float* __restrict__ k2, const float* __restrict__ b2,
    const float* __restrict__ k3, const float* __restrict__ b3,
    float* __restrict__ wout)
{
    __shared__ float sPart[4][4][256];   // [wave][par][n]  16 KB
    __shared__ float sH2[4][256];        // [par][n]         4 KB
    __shared__ float sR[4][4][16];       // [wave][par][c]   1 KB
    const int tid  = threadIdx.x;
    const int lane = tid & 63;
    const int w    = tid >> 6;

    // ---- phase 1a: h1 for this wave's m-slice (m = w*64+lane), 4 parities
    const int m = w * 64 + lane;
    const float k10 = k1[m], k11 = k1[HID + m], k12 = k1[2 * HID + m];
    const float b1m = b1[m];
    float h1r[4];
    h1r[0] = fmaxf(0.5f * k12 + b1m, 0.0f);
    h1r[1] = fmaxf(0.5f * k11 + 0.5f * k12 + b1m, 0.0f);
    h1r[2] = fmaxf(0.5f * k10 + 0.5f * k12 + b1m, 0.0f);
    h1r[3] = fmaxf(0.5f * k10 + 0.5f * k11 + 0.5f * k12 + b1m, 0.0f);

    // ---- phase 1b: partial h2: wave w covers m in [64w,64w+64),
    //      cols 4*lane..4*lane+3 (float4), all 4 parities.
    float4 acc[4];
#pragma unroll
    for (int p = 0; p < 4; ++p) acc[p] = make_float4(0.f, 0.f, 0.f, 0.f);
    const float* k2p = k2 + (w * 64) * HID + 4 * lane;
#pragma unroll
    for (int i = 0; i < 64; ++i) {
        const float4 kv = *reinterpret_cast<const float4*>(k2p + i * HID);
#pragma unroll
        for (int p = 0; p < 4; ++p) {
            const float hm = rdlane(h1r[p], i);
            acc[p].x = fmaf(hm, kv.x, acc[p].x);
            acc[p].y = fmaf(hm, kv.y, acc[p].y);
            acc[p].z = fmaf(hm, kv.z, acc[p].z);
            acc[p].w = fmaf(hm, kv.w, acc[p].w);
        }
    }
#pragma unroll
    for (int p = 0; p < 4; ++p)
        *reinterpret_cast<float4*>(&sPart[w][p][4 * lane]) = acc[p];
    __syncthreads();

    // ---- phase 1c: reduce 4 waves -> h2 (relu) in LDS
    const float b2v = b2[tid];
#pragma unroll
    for (int p = 0; p < 4; ++p) {
        const float s = b2v + sPart[0][p][tid] + sPart[1][p][tid]
                      + sPart[2][p][tid] + sPart[3][p][tid];
        sH2[p][tid] = fmaxf(s, 0.0f);
    }
    __syncthreads();

    // ---- phase 2: this block's 16 k3 columns.
    // c = tid&15 (column), slot = w*4 + (lane>>4) in [0,16): m-range of 16.
    const int c    = tid & 15;
    const int sg   = lane >> 4;           // 0..3
    const int mbase = (w * 4 + sg) * 16;  // 0..240, step 16
    const int n    = blockIdx.x * 16 + c; // k3 column 0..1727

    // k3 values for this thread's 16 m's (coalesced across the 16 c-lanes)
    float kv[16];
#pragma unroll
    for (int j = 0; j < 16; ++j)
        kv[j] = k3[(size_t)(mbase + j) * NW + n];

    // h2 fragments from LDS (vector reads, broadcast across same-sg lanes)
    float pr[4];
#pragma unroll
    for (int p = 0; p < 4; ++p) {
        float s = 0.0f;
#pragma unroll
        for (int q = 0; q < 4; ++q) {
            const float4 h4 = *reinterpret_cast<const float4*>(
                &sH2[p][mbase + 4 * q]);
            s = fmaf(h4.x, kv[4 * q + 0], s);
            s = fmaf(h4.y, kv[4 * q + 1], s);
            s = fmaf(h4.z, kv[4 * q + 2], s);
            s = fmaf(h4.w, kv[4 * q + 3], s);
        }
        pr[p] = s;
    }

    // reduce over the 4 slot-groups within the wave (lane bits 4,5)
#pragma unroll
    for (int p = 0; p < 4; ++p) {
        pr[p] += __shfl_xor(pr[p], 16);
        pr[p] += __shfl_xor(pr[p], 32);
    }
    if (lane < 16) {
#pragma unroll
        for (int p = 0; p < 4; ++p) sR[w][p][lane] = pr[p];
    }
    __syncthreads();

    // final: threads 0..63 -> (p = t>>4, c = t&15), reduce 4 waves + b3
    if (tid < 64) {
        const int fp = tid >> 4, fc = tid & 15;
        const int fn = blockIdx.x * 16 + fc;
        const float total = b3[fn] + sR[0][fp][fc] + sR[1][fp][fc]
                          + sR[2][fp][fc] + sR[3][fp][fc];
        // fn = ((pp*3+q)*64 + ch)*3 + o  ->  [par][o][pq][ch]
        const int o = fn % 3;
        const int rest = fn / 3;
        const int cch = rest & 63;
        const int pq = rest >> 6;
        wout[fp * NW + (o * 9 + pq) * 64 + cch] = total;
    }
}

// ---------------------------------------------------------------------------
// K2: the einsum (validated). Wave = 4 parities x 16 c4-chunks, PPW pixels
// per wave, column ring buffer, weights register-stationary. Grid 512 x 256.
// ---------------------------------------------------------------------------
__global__ __launch_bounds__(256) void upscale_kernel(
    const float* __restrict__ feat, const float* __restrict__ wts,
    float* __restrict__ out)
{
    const int tid  = threadIdx.x;
    const int lane = tid & 63;
    const int w    = tid >> 6;
    const int gw   = blockIdx.x * 4 + w;     // 0..2047
    const int iy   = gw >> 4;                // input row 0..127
    const int ix0  = (gw & 15) * PPW;        // input col base
    const int par  = lane >> 4;              // 0..3
    const int c4   = lane & 15;              // channel quad
    const int pi = par >> 1, pj = par & 1;

    const bool rv0 = iy > 0, rv2 = iy < H_IN - 1;
    const float4 fz = make_float4(0.f, 0.f, 0.f, 0.f);
    const float* frow0 = feat + ((iy - 1) * W_IN) * C_IN + c4 * 4;
    const float* frow1 = feat + ((iy    ) * W_IN) * C_IN + c4 * 4;
    const float* frow2 = feat + ((iy + 1) * W_IN) * C_IN + c4 * 4;

    float4 fc0[3], fc1[3], fc2[3];
    auto ldcol = [&](int cc, float4& a, float4& b, float4& c) {
        if ((unsigned)cc < (unsigned)W_IN) {
            a = rv0 ? *reinterpret_cast<const float4*>(frow0 + cc * C_IN) : fz;
            b =       *reinterpret_cast<const float4*>(frow1 + cc * C_IN);
            c = rv2 ? *reinterpret_cast<const float4*>(frow2 + cc * C_IN) : fz;
        } else { a = fz; b = fz; c = fz; }
    };
    ldcol(ix0 - 1, fc0[0], fc1[0], fc2[0]);
    ldcol(ix0,     fc0[1], fc1[1], fc2[1]);

    float4 wreg[3][9];
#pragma unroll
    for (int o = 0; o < 3; ++o)
#pragma unroll
        for (int pq = 0; pq < 9; ++pq)
            wreg[o][pq] = *reinterpret_cast<const float4*>(
                wts + ((par * 3 + o) * 9 + pq) * 64 + c4 * 4);

#pragma unroll
    for (int g = 0; g < PPW; ++g) {
        const int sNew = (g + 2) % 3;
        ldcol(ix0 + g + 1, fc0[sNew], fc1[sNew], fc2[sNew]);

        float acc0 = 0.f, acc1 = 0.f, acc2 = 0.f;
#pragma unroll
        for (int q = 0; q < 3; ++q) {
            const int s = (g + q) % 3;
            const float4 f0 = fc0[s], f1 = fc1[s], f2 = fc2[s];
            const int pq0 = q, pq1 = 3 + q, pq2 = 6 + q;
            acc0 = fmaf(f0.x, wreg[0][pq0].x, acc0);
            acc0 = fmaf(f0.y, wreg[0][pq0].y, acc0);
            acc0 = fmaf(f0.z, wreg[0][pq0].z, acc0);
            acc0 = fmaf(f0.w, wreg[0][pq0].w, acc0);
            acc1 = fmaf(f0.x, wreg[1][pq0].x, acc1);
            acc1 = fmaf(f0.y, wreg[1][pq0].y, acc1);
            acc1 = fmaf(f0.z, wreg[1][pq0].z, acc1);
            acc1 = fmaf(f0.w, wreg[1][pq0].w, acc1);
            acc2 = fmaf(f0.x, wreg[2][pq0].x, acc2);
            acc2 = fmaf(f0.y, wreg[2][pq0].y, acc2);
            acc2 = fmaf(f0.z, wreg[2][pq0].z, acc2);
            acc2 = fmaf(f0.w, wreg[2][pq0].w, acc2);

            acc0 = fmaf(f1.x, wreg[0][pq1].x, acc0);
            acc0 = fmaf(f1.y, wreg[0][pq1].y, acc0);
            acc0 = fmaf(f1.z, wreg[0][pq1].z, acc0);
            acc0 = fmaf(f1.w, wreg[0][pq1].w, acc0);
            acc1 = fmaf(f1.x, wreg[1][pq1].x, acc1);
            acc1 = fmaf(f1.y, wreg[1][pq1].y, acc1);
            acc1 = fmaf(f1.z, wreg[1][pq1].z, acc1);
            acc1 = fmaf(f1.w, wreg[1][pq1].w, acc1);
            acc2 = fmaf(f1.x, wreg[2][pq1].x, acc2);
            acc2 = fmaf(f1.y, wreg[2][pq1].y, acc2);
            acc2 = fmaf(f1.z, wreg[2][pq1].z, acc2);
            acc2 = fmaf(f1.w, wreg[2][pq1].w, acc2);

            acc0 = fmaf(f2.x, wreg[0][pq2].x, acc0);
            acc0 = fmaf(f2.y, wreg[0][pq2].y, acc0);
            acc0 = fmaf(f2.z, wreg[0][pq2].z, acc0);
            acc0 = fmaf(f2.w, wreg[0][pq2].w, acc0);
            acc1 = fmaf(f2.x, wreg[1][pq2].x, acc1);
            acc1 = fmaf(f2.y, wreg[1][pq2].y, acc1);
            acc1 = fmaf(f2.z, wreg[1][pq2].z, acc1);
            acc1 = fmaf(f2.w, wreg[1][pq2].w, acc1);
            acc2 = fmaf(f2.x, wreg[2][pq2].x, acc2);
            acc2 = fmaf(f2.y, wreg[2][pq2].y, acc2);
            acc2 = fmaf(f2.z, wreg[2][pq2].z, acc2);
            acc2 = fmaf(f2.w, wreg[2][pq2].w, acc2);
        }

        // 8-shuffle reduction over 16 lanes for 3 values
        acc0 += __shfl_xor(acc0, 1); acc0 += __shfl_xor(acc0, 2);
        acc1 += __shfl_xor(acc1, 1); acc1 += __shfl_xor(acc1, 2);
        acc2 += __shfl_xor(acc2, 1); acc2 += __shfl_xor(acc2, 2);
        const int j = c4 & 3;
        float v = (j == 0) ? acc0 : ((j == 1) ? acc1 : acc2);
        v += __shfl_xor(v, 4);
        v += __shfl_xor(v, 8);
        if (c4 < 3) {
            const int oy = 2 * iy + pi;
            const int ox = 2 * (ix0 + g) + pj;
            out[(oy * OUT_W + ox) * OUT_C + c4] = v;
        }
    }
}

// ---------------------------------------------------------------------------
extern "C" void kernel_launch(void* const* d_in, const int* in_sizes, int n_in,
                              void* d_out, int out_size, void* d_ws, size_t ws_size,
                              hipStream_t stream)
{
    const float* feat = (const float*)d_in[0];
    const float* k1   = (const float*)d_in[1];
    const float* b1   = (const float*)d_in[2];
    const float* k2   = (const float*)d_in[3];
    const float* b2   = (const float*)d_in[4];
    const float* k3   = (const float*)d_in[5];
    const float* b3   = (const float*)d_in[6];
    float* out = (float*)d_out;
    float* wts = (float*)d_ws;   // 4*NW floats, [par][o][pq][c]

    mlp_all_kernel<<<108, 256, 0, stream>>>(k1, b1, k2, b2, k3, b3, wts);
    upscale_kernel<<<512, 256, 0, stream>>>(feat, wts, out);
}

// Round 9
// 17.577 us; speedup vs baseline: 8.2519x; 1.3300x over previous
//
#include <hip/hip_runtime.h>
#include <hip/hip_bf16.h>

// Problem constants (fixed: H=W=128, C=64, K=3, HID=256, OUT_C=3, scale=2)
#define H_IN 128
#define W_IN 128
#define C_IN 64
#define HID 256
#define OUT_C 3
#define OUT_W 256
#define NW 1728   // 3*3*64*3 weights per parity
#define PPW 8     // pixels per wave in the einsum phase

__device__ __forceinline__ float rdlane(float v, int l) {
    return __int_as_float(__builtin_amdgcn_readlane(__float_as_int(v), l));
}

// ---------------------------------------------------------------------------
// K1: ENTIRE MLP, one kernel, 108 blocks x 256. Identical math to R8
// (validated); only change: the 16 k3 loads are issued FIRST so their cold
// HBM latency hides under the k2 matmul.
// ---------------------------------------------------------------------------
__global__ __launch_bounds__(256) void mlp_all_kernel(
    const float* __restrict__ k1, const float* __restrict__ b1,
    const float* __restrict__ k2, const float* __restrict__ b2,
    const float* __restrict__ k3, const float* __restrict__ b3,
    float* __restrict__ wout)
{
    __shared__ float sPart[4][4][256];   // [wave][par][n]  16 KB
    __shared__ float sH2[4][256];        // [par][n]         4 KB
    __shared__ float sR[4][4][16];       // [wave][par][c]   1 KB
    const int tid  = threadIdx.x;
    const int lane = tid & 63;
    const int w    = tid >> 6;

    // ---- phase 2 address setup + EARLY k3 loads (independent of h2)
    const int c    = tid & 15;
    const int sg   = lane >> 4;           // 0..3
    const int mbase = (w * 4 + sg) * 16;  // 0..240, step 16
    const int n    = blockIdx.x * 16 + c; // k3 column 0..1727
    float kv[16];
#pragma unroll
    for (int j = 0; j < 16; ++j)
        kv[j] = k3[(size_t)(mbase + j) * NW + n];

    // ---- phase 1a: h1 for this wave's m-slice (m = w*64+lane), 4 parities
    const int m = w * 64 + lane;
    const float k10 = k1[m], k11 = k1[HID + m], k12 = k1[2 * HID + m];
    const float b1m = b1[m];
    float h1r[4];
    h1r[0] = fmaxf(0.5f * k12 + b1m, 0.0f);
    h1r[1] = fmaxf(0.5f * k11 + 0.5f * k12 + b1m, 0.0f);
    h1r[2] = fmaxf(0.5f * k10 + 0.5f * k12 + b1m, 0.0f);
    h1r[3] = fmaxf(0.5f * k10 + 0.5f * k11 + 0.5f * k12 + b1m, 0.0f);

    // ---- phase 1b: partial h2: wave w covers m in [64w,64w+64),
    //      cols 4*lane..4*lane+3 (float4), all 4 parities.
    float4 acc[4];
#pragma unroll
    for (int p = 0; p < 4; ++p) acc[p] = make_float4(0.f, 0.f, 0.f, 0.f);
    const float* k2p = k2 + (w * 64) * HID + 4 * lane;
#pragma unroll
    for (int i = 0; i < 64; ++i) {
        const float4 kvv = *reinterpret_cast<const float4*>(k2p + i * HID);
#pragma unroll
        for (int p = 0; p < 4; ++p) {
            const float hm = rdlane(h1r[p], i);
            acc[p].x = fmaf(hm, kvv.x, acc[p].x);
            acc[p].y = fmaf(hm, kvv.y, acc[p].y);
            acc[p].z = fmaf(hm, kvv.z, acc[p].z);
            acc[p].w = fmaf(hm, kvv.w, acc[p].w);
        }
    }
#pragma unroll
    for (int p = 0; p < 4; ++p)
        *reinterpret_cast<float4*>(&sPart[w][p][4 * lane]) = acc[p];
    __syncthreads();

    // ---- phase 1c: reduce 4 waves -> h2 (relu) in LDS
    const float b2v = b2[tid];
#pragma unroll
    for (int p = 0; p < 4; ++p) {
        const float s = b2v + sPart[0][p][tid] + sPart[1][p][tid]
                      + sPart[2][p][tid] + sPart[3][p][tid];
        sH2[p][tid] = fmaxf(s, 0.0f);
    }
    __syncthreads();

    // ---- phase 2: this block's 16 k3 columns (kv already in registers)
    float pr[4];
#pragma unroll
    for (int p = 0; p < 4; ++p) {
        float s = 0.0f;
#pragma unroll
        for (int q = 0; q < 4; ++q) {
            const float4 h4 = *reinterpret_cast<const float4*>(
                &sH2[p][mbase + 4 * q]);
            s = fmaf(h4.x, kv[4 * q + 0], s);
            s = fmaf(h4.y, kv[4 * q + 1], s);
            s = fmaf(h4.z, kv[4 * q + 2], s);
            s = fmaf(h4.w, kv[4 * q + 3], s);
        }
        pr[p] = s;
    }
#pragma unroll
    for (int p = 0; p < 4; ++p) {
        pr[p] += __shfl_xor(pr[p], 16);
        pr[p] += __shfl_xor(pr[p], 32);
    }
    if (lane < 16) {
#pragma unroll
        for (int p = 0; p < 4; ++p) sR[w][p][lane] = pr[p];
    }
    __syncthreads();

    if (tid < 64) {
        const int fp = tid >> 4, fc = tid & 15;
        const int fn = blockIdx.x * 16 + fc;
        const float total = b3[fn] + sR[0][fp][fc] + sR[1][fp][fc]
                          + sR[2][fp][fc] + sR[3][fp][fc];
        // fn = ((pp*3+q)*64 + ch)*3 + o  ->  [par][o][pq][ch]
        const int o = fn % 3;
        const int rest = fn / 3;
        const int cch = rest & 63;
        const int pq = rest >> 6;
        wout[fp * NW + (o * 9 + pq) * 64 + cch] = total;
    }
}

// ---------------------------------------------------------------------------
// K2: the einsum with block-level LDS staging of the feature tile.
// Grid 512 x 256: bid -> (iy = bid>>2, cg = bid&3). Block stages rows
// iy-1..iy+1, cols [cg*32-1, cg*32+33) x 64 ch (26 KB) in ONE coalesced
// latency round, then computes from LDS. FMA/reduction code = validated R8.
// ---------------------------------------------------------------------------
__global__ __launch_bounds__(256) void upscale_kernel(
    const float* __restrict__ feat, const float* __restrict__ wts,
    float* __restrict__ out)
{
    __shared__ float sF[3][34][64];      // 26112 B
    const int tid  = threadIdx.x;
    const int lane = tid & 63;
    const int w    = tid >> 6;
    const int iy   = blockIdx.x >> 2;    // input row 0..127
    const int cg   = blockIdx.x & 3;     // column group (32 cols)
    const int par  = lane >> 4;          // 0..3
    const int c4   = lane & 15;          // channel quad
    const int pi = par >> 1, pj = par & 1;
    const float4 fz = make_float4(0.f, 0.f, 0.f, 0.f);

    // ---- weight preamble loads issued first (independent of staging)
    float4 wreg[3][9];
#pragma unroll
    for (int o = 0; o < 3; ++o)
#pragma unroll
        for (int pq = 0; pq < 9; ++pq)
            wreg[o][pq] = *reinterpret_cast<const float4*>(
                wts + ((par * 3 + o) * 9 + pq) * 64 + c4 * 4);

    // ---- stage the 3x34x64 feature tile (zero-padded at borders)
    const int cbase = cg * 32 - 1;
#pragma unroll
    for (int idx = tid, it = 0; it < 7; ++it, idx += 256) {
        if (idx < 1632) {                      // 3*34*16 float4 elements
            const int c4i = idx & 15;
            const int t   = idx >> 4;
            const int col = t % 34;
            const int r   = t / 34;
            const int grow = iy - 1 + r;
            const int gcol = cbase + col;
            float4 v = fz;
            if ((unsigned)grow < (unsigned)H_IN && (unsigned)gcol < (unsigned)W_IN)
                v = *reinterpret_cast<const float4*>(
                    feat + (grow * W_IN + gcol) * C_IN + c4i * 4);
            *reinterpret_cast<float4*>(&sF[r][col][c4i * 4]) = v;
        }
    }
    __syncthreads();

    // ---- compute: wave w covers pixels ix = cg*32 + w*8 + g, g = 0..7.
    // Local LDS col of global col X is X - cbase; window col (q) for pixel g
    // is local w*8+g+q. Ring slots preserved from the validated code.
    float4 fc0[3], fc1[3], fc2[3];
    auto ldl = [&](int col, float4& a, float4& b, float4& c) {
        a = *reinterpret_cast<const float4*>(&sF[0][col][c4 * 4]);
        b = *reinterpret_cast<const float4*>(&sF[1][col][c4 * 4]);
        c = *reinterpret_cast<const float4*>(&sF[2][col][c4 * 4]);
    };
    ldl(w * 8 + 0, fc0[0], fc1[0], fc2[0]);
    ldl(w * 8 + 1, fc0[1], fc1[1], fc2[1]);

#pragma unroll
    for (int g = 0; g < PPW; ++g) {
        const int sNew = (g + 2) % 3;
        ldl(w * 8 + g + 2, fc0[sNew], fc1[sNew], fc2[sNew]);

        float acc0 = 0.f, acc1 = 0.f, acc2 = 0.f;
#pragma unroll
        for (int q = 0; q < 3; ++q) {
            const int s = (g + q) % 3;
            const float4 f0 = fc0[s], f1 = fc1[s], f2 = fc2[s];
            const int pq0 = q, pq1 = 3 + q, pq2 = 6 + q;
            acc0 = fmaf(f0.x, wreg[0][pq0].x, acc0);
            acc0 = fmaf(f0.y, wreg[0][pq0].y, acc0);
            acc0 = fmaf(f0.z, wreg[0][pq0].z, acc0);
            acc0 = fmaf(f0.w, wreg[0][pq0].w, acc0);
            acc1 = fmaf(f0.x, wreg[1][pq0].x, acc1);
            acc1 = fmaf(f0.y, wreg[1][pq0].y, acc1);
            acc1 = fmaf(f0.z, wreg[1][pq0].z, acc1);
            acc1 = fmaf(f0.w, wreg[1][pq0].w, acc1);
            acc2 = fmaf(f0.x, wreg[2][pq0].x, acc2);
            acc2 = fmaf(f0.y, wreg[2][pq0].y, acc2);
            acc2 = fmaf(f0.z, wreg[2][pq0].z, acc2);
            acc2 = fmaf(f0.w, wreg[2][pq0].w, acc2);

            acc0 = fmaf(f1.x, wreg[0][pq1].x, acc0);
            acc0 = fmaf(f1.y, wreg[0][pq1].y, acc0);
            acc0 = fmaf(f1.z, wreg[0][pq1].z, acc0);
            acc0 = fmaf(f1.w, wreg[0][pq1].w, acc0);
            acc1 = fmaf(f1.x, wreg[1][pq1].x, acc1);
            acc1 = fmaf(f1.y, wreg[1][pq1].y, acc1);
            acc1 = fmaf(f1.z, wreg[1][pq1].z, acc1);
            acc1 = fmaf(f1.w, wreg[1][pq1].w, acc1);
            acc2 = fmaf(f1.x, wreg[2][pq1].x, acc2);
            acc2 = fmaf(f1.y, wreg[2][pq1].y, acc2);
            acc2 = fmaf(f1.z, wreg[2][pq1].z, acc2);
            acc2 = fmaf(f1.w, wreg[2][pq1].w, acc2);

            acc0 = fmaf(f2.x, wreg[0][pq2].x, acc0);
            acc0 = fmaf(f2.y, wreg[0][pq2].y, acc0);
            acc0 = fmaf(f2.z, wreg[0][pq2].z, acc0);
            acc0 = fmaf(f2.w, wreg[0][pq2].w, acc0);
            acc1 = fmaf(f2.x, wreg[1][pq2].x, acc1);
            acc1 = fmaf(f2.y, wreg[1][pq2].y, acc1);
            acc1 = fmaf(f2.z, wreg[1][pq2].z, acc1);
            acc1 = fmaf(f2.w, wreg[1][pq2].w, acc1);
            acc2 = fmaf(f2.x, wreg[2][pq2].x, acc2);
            acc2 = fmaf(f2.y, wreg[2][pq2].y, acc2);
            acc2 = fmaf(f2.z, wreg[2][pq2].z, acc2);
            acc2 = fmaf(f2.w, wreg[2][pq2].w, acc2);
        }

        // 8-shuffle reduction over 16 lanes for 3 values
        acc0 += __shfl_xor(acc0, 1); acc0 += __shfl_xor(acc0, 2);
        acc1 += __shfl_xor(acc1, 1); acc1 += __shfl_xor(acc1, 2);
        acc2 += __shfl_xor(acc2, 1); acc2 += __shfl_xor(acc2, 2);
        const int j = c4 & 3;
        float v = (j == 0) ? acc0 : ((j == 1) ? acc1 : acc2);
        v += __shfl_xor(v, 4);
        v += __shfl_xor(v, 8);
        if (c4 < 3) {
            const int oy = 2 * iy + pi;
            const int ox = 2 * (cg * 32 + w * 8 + g) + pj;
            out[(oy * OUT_W + ox) * OUT_C + c4] = v;
        }
    }
}

// ---------------------------------------------------------------------------
extern "C" void kernel_launch(void* const* d_in, const int* in_sizes, int n_in,
                              void* d_out, int out_size, void* d_ws, size_t ws_size,
                              hipStream_t stream)
{
    const float* feat = (const float*)d_in[0];
    const float* k1   = (const float*)d_in[1];
    const float* b1   = (const float*)d_in[2];
    const float* k2   = (const float*)d_in[3];
    const float* b2   = (const float*)d_in[4];
    const float* k3   = (const float*)d_in[5];
    const float* b3   = (const float*)d_in[6];
    float* out = (float*)d_out;
    float* wts = (float*)d_ws;   // 4*NW floats, [par][o][pq][c]

    mlp_all_kernel<<<108, 256, 0, stream>>>(k1, b1, k2, b2, k3, b3, wts);
    upscale_kernel<<<512, 256, 0, stream>>>(feat, wts, out);
}